// Round 17
// baseline (3629.048 us; speedup 1.0000x reference)
//
#include <hip/hip_runtime.h>
#include <hip/hip_fp16.h>

// Bidirectional 2-layer LSTM: B=32, T=1024, IN=256, H=256.
// ws layout: xg  f16 [2][32][1024][1024]        = 134,217,728 B
//            hbt u64 [2][32][2 parity][256]     =     262,144 B (pair-tagged h)
// total = 134,479,872 B
//
// Tag protocol per (d,b) (layer base B): producer at step st stores
// (B+st+1, pair) into parity st&1; consumer at step st polls parity (st+1)&1
// for tag B+st. L0 base=1, L1 base=4096; hbt memset 0 each launch.
// No-missed-tag: the peer that would overwrite my polled slot (tag B+st+2)
// must pass ITS barrier(st+1), which needs MY h(st) store, which follows MY
// poll(st) success. Chain verified r13-r14.
//
// recur15 = r14 (best, 1290us) + r16 lessons:
//  KEEP from r14: group-of-4 topology, pair-packed u64 exchange (halves
//    traffic - verified), 96 one-pair pollers, tag algebra.
//  CHANGE: thread = jl*4+q (full 256-k, one gate row, 128 pinned W regs) ->
//    no kh split -> no scr, no kh-reduce; gate gather = 3 quad_perm DPP
//    (xor1/xor2 within quad - NO ds_swizzle); epilogue inline in all 4
//    compute waves (producers tid%4==0); pair-partner h via ONE
//    __shfl_down(4)/step; ONE barrier/step; 384 threads (6 waves, r14 had
//    2.5 idle); s_setprio(1) around compute (T5: role-split waves).
// Single-barrier safety: compute(st) reads hl[par] written by poll(st)
// [pre-barrier(st), foreign cells] and producers(st-1) [own cells, written
// during compute(st-1), pre-barrier(st)]. Next writers of hl[par]:
// producers(st+1) write after barrier(st+1); poll(st+2) runs after
// barrier(st+1) too (pollers pass it) - all after compute(st) reads. Disjoint
// cells within a parity. Deadlock-free by induction (poll(st) <- peers'
// compute(st-1) <- their barrier(st-1) <- ... <- init).

#define T_LEN 1024
#define BATCH 32
#define HID   256
#define G4    1024

struct __align__(16) Half8 { __half h[8]; };

typedef _Float16 f16x2 __attribute__((ext_vector_type(2)));
typedef _Float16 half8_t __attribute__((ext_vector_type(8)));
typedef float f32x4 __attribute__((ext_vector_type(4)));

__device__ __forceinline__ f16x2 pack_f16x2(float lo, float hi) {
    f16x2 r; r.x = (_Float16)lo; r.y = (_Float16)hi; return r;
}
__device__ __forceinline__ float dot2acc(f16x2 a, f16x2 b, float c) {
#if __has_builtin(__builtin_amdgcn_fdot2)
    return __builtin_amdgcn_fdot2(a, b, c, false);
#else
    return c + (float)a.x * (float)b.x + (float)a.y * (float)b.y;
#endif
}

template <int CTRL>
__device__ __forceinline__ float qpermf(float v) {
    int i = __builtin_bit_cast(int, v);
    int r = __builtin_amdgcn_update_dpp(i, i, CTRL, 0xF, 0xF, true);
    return __builtin_bit_cast(float, r);
}

__device__ __forceinline__ float sigm(float x) { return 1.0f / (1.0f + __expf(-x)); }
__device__ __forceinline__ float tanh_fast(float x) {
    float e = __expf(2.f * x);            // inf-safe
    return 1.f - 2.f / (e + 1.f);
}

#define WH(i) __builtin_bit_cast(f16x2, wh[i])

// ---- MFMA projection (r13, unchanged): xg = A*W^T + bias, fp16 out ----
__global__ __launch_bounds__(256, 2) void proj_mfma(
    const float* __restrict__ A, int K,
    const float* __restrict__ Wf, const float* __restrict__ Wr,
    const float* __restrict__ bih_f, const float* __restrict__ bhh_f,
    const float* __restrict__ bih_r, const float* __restrict__ bhh_r,
    __half* __restrict__ xg)
{
    const int dir = blockIdx.z;
    const float* __restrict__ W   = dir ? Wr    : Wf;
    const float* __restrict__ bih = dir ? bih_r : bih_f;
    const float* __restrict__ bhh = dir ? bhh_r : bhh_f;
    __half* __restrict__ outp = xg + (size_t)dir * ((size_t)BATCH * T_LEN * G4);

    __shared__ char psm[36864];
    __half* As = (__half*)psm;                // [128][72]
    __half* Bs = (__half*)(psm + 18432);      // [128][72]

    const int tid  = threadIdx.x;
    const int lane = tid & 63;
    const int wave = tid >> 6;
    const int wm   = wave >> 1;
    const int wn   = wave & 1;
    const int fr   = lane & 15;
    const int fk   = lane >> 4;
    const int m0   = blockIdx.y * 128;
    const int n0   = blockIdx.x * 128;

    float biasv[4];
    #pragma unroll
    for (int ni = 0; ni < 4; ++ni) {
        int n = n0 + wn * 64 + ni * 16 + fr;
        biasv[ni] = bih[n] + bhh[n];
    }

    f32x4 acc[4][4];
    #pragma unroll
    for (int mi = 0; mi < 4; ++mi)
        #pragma unroll
        for (int ni = 0; ni < 4; ++ni)
            acc[mi][ni] = (f32x4){0.f, 0.f, 0.f, 0.f};

    for (int k0 = 0; k0 < K; k0 += 64) {
        #pragma unroll
        for (int it = 0; it < 4; ++it) {
            int t2  = tid + it * 256;
            int row = t2 >> 3;
            int ks  = (t2 & 7) * 8;
            const float* pa = &A[(size_t)(m0 + row) * K + k0 + ks];
            const float* pb = &W[(size_t)(n0 + row) * K + k0 + ks];
            float4 a0 = *reinterpret_cast<const float4*>(pa);
            float4 a1 = *reinterpret_cast<const float4*>(pa + 4);
            float4 b0 = *reinterpret_cast<const float4*>(pb);
            float4 b1 = *reinterpret_cast<const float4*>(pb + 4);
            Half8 ha, hb;
            ha.h[0] = __float2half(a0.x); ha.h[1] = __float2half(a0.y);
            ha.h[2] = __float2half(a0.z); ha.h[3] = __float2half(a0.w);
            ha.h[4] = __float2half(a1.x); ha.h[5] = __float2half(a1.y);
            ha.h[6] = __float2half(a1.z); ha.h[7] = __float2half(a1.w);
            hb.h[0] = __float2half(b0.x); hb.h[1] = __float2half(b0.y);
            hb.h[2] = __float2half(b0.z); hb.h[3] = __float2half(b0.w);
            hb.h[4] = __float2half(b1.x); hb.h[5] = __float2half(b1.y);
            hb.h[6] = __float2half(b1.z); hb.h[7] = __float2half(b1.w);
            *reinterpret_cast<Half8*>(&As[row * 72 + ks]) = ha;
            *reinterpret_cast<Half8*>(&Bs[row * 72 + ks]) = hb;
        }
        __syncthreads();

        #pragma unroll
        for (int kk = 0; kk < 2; ++kk) {
            half8_t af[4], bf[4];
            #pragma unroll
            for (int mi = 0; mi < 4; ++mi)
                af[mi] = *reinterpret_cast<const half8_t*>(
                    &As[(wm * 64 + mi * 16 + fr) * 72 + kk * 32 + fk * 8]);
            #pragma unroll
            for (int ni = 0; ni < 4; ++ni)
                bf[ni] = *reinterpret_cast<const half8_t*>(
                    &Bs[(wn * 64 + ni * 16 + fr) * 72 + kk * 32 + fk * 8]);
            #pragma unroll
            for (int mi = 0; mi < 4; ++mi)
                #pragma unroll
                for (int ni = 0; ni < 4; ++ni)
                    acc[mi][ni] = __builtin_amdgcn_mfma_f32_16x16x32_f16(
                        af[mi], bf[ni], acc[mi][ni], 0, 0, 0);
        }
        __syncthreads();
    }

    __half* Cs = (__half*)psm;
    #pragma unroll
    for (int mi = 0; mi < 4; ++mi)
        #pragma unroll
        for (int ni = 0; ni < 4; ++ni) {
            #pragma unroll
            for (int i = 0; i < 4; ++i) {
                int row = wm * 64 + mi * 16 + fk * 4 + i;
                int col = wn * 64 + ni * 16 + fr;
                Cs[row * 136 + col] = __float2half(acc[mi][ni][i] + biasv[ni]);
            }
        }
    __syncthreads();
    #pragma unroll
    for (int it = 0; it < 8; ++it) {
        int slot = it * 256 + tid;
        int row  = slot >> 4;
        int c8   = (slot & 15) * 8;
        Half8 v = *reinterpret_cast<const Half8*>(&Cs[row * 136 + c8]);
        *reinterpret_cast<Half8*>(&outp[(size_t)(m0 + row) * G4 + n0 + c8]) = v;
    }
}

// ---- cooperative recurrence: full-k threads, DPP gate gather, 1 barrier ----
// bid = jq*64 + d*32 + b (4 jq of (d,b) share bid%8 -> same-XCD heuristic).
// compute tid<256: jl = tid>>2 (cell in quarter), q = tid&3 (gate).
// pollers tid in [256,352): one foreign u64 pair-slot each. 384 threads.
extern "C" __global__ __launch_bounds__(384, 2) void recur15_kernel(
    const __half* __restrict__ xg,
    const float* __restrict__ Whh_f,           // [1024][256]
    const float* __restrict__ Whh_r,
    float* __restrict__ outp,                  // [32][1024][512]
    unsigned long long* __restrict__ hbt,      // [2][32][2][256] (128/parity used)
    unsigned int tagbase)
{
    extern __shared__ char smem[];             // 96 KB -> 1 block/CU
    __half* hl = (__half*)smem;                // [2 parity][256 j]

    const int tid = threadIdx.x;
    const int bid = blockIdx.x;
    const int jq  = bid >> 6;
    const int d   = (bid >> 5) & 1;
    const int b   = bid & 31;
    const float* __restrict__ Whh = d ? Whh_r : Whh_f;

    const int jl = (tid >> 2) & 63;            // cell within quarter
    const int q  = tid & 3;                    // gate i/f/g/o
    const int cell_my = jq * 64 + jl;
    const int n_my = (q << 8) + cell_my;

    // --- one-time (compute threads): full W row (256 f32) -> 128 packed half2 ---
    unsigned wh[128];
    if (tid < 256) {
        const float* wrow = Whh + (size_t)n_my * HID;
        #pragma unroll
        for (int i = 0; i < 64; ++i) {
            float4 w4 = *reinterpret_cast<const float4*>(&wrow[i * 4]);
            wh[2 * i]     = __builtin_bit_cast(unsigned, pack_f16x2(w4.x, w4.y));
            wh[2 * i + 1] = __builtin_bit_cast(unsigned, pack_f16x2(w4.z, w4.w));
        }
        #pragma unroll
        for (int i = 0; i < 128; ++i) asm volatile("" : "+v"(wh[i]));  // no remat
    }

    unsigned long long* hb = hbt + (size_t)(d * 32 + b) * 512;   // [parity][256]

    // init: h[-1]=0 -> parity-1 pair tags (32 slots) + hl[0] own cells
    if (tid < 32) {
        __hip_atomic_store(&hb[256 + jq * 32 + tid],
                           (unsigned long long)tagbase << 32,
                           __ATOMIC_RELAXED, __HIP_MEMORY_SCOPE_AGENT);
    }
    if (tid < 64) hl[0 * 256 + jq * 64 + tid] = __float2half(0.f);
    __syncthreads();

    // pollers: one foreign pair-slot each
    const bool isPoll = (tid >= 256) && (tid < 352);
    int pslot = 0, pdst = 0;
    if (isPoll) {
        int u  = tid - 256;            // 0..95
        int fq = u >> 5;               // 0..2
        int qq = fq + (fq >= jq);      // skip own quarter
        int pi = u & 31;
        pslot  = qq * 32 + pi;
        pdst   = qq * 64 + pi * 2;     // __half index (even)
    }

    const __half* __restrict__ xgp =
        xg + ((size_t)(d * BATCH + b)) * T_LEN * G4 + n_my;

    float c_state = 0.f;               // valid at q==0 lanes

    for (int st = 0; st < T_LEN; ++st) {
        const int t = d ? (T_LEN - 1 - st) : st;
        const int par = st & 1;

        // poll: stage foreign h(st-1) (parity (st+1)&1, tag B+st) into hl[par]
        if (isPoll) {
            const unsigned exp = tagbase + (unsigned)st;
            unsigned long long* src = &hb[(size_t)((st + 1) & 1) * 256 + pslot];
            unsigned long long v =
                __hip_atomic_load(src, __ATOMIC_RELAXED, __HIP_MEMORY_SCOPE_AGENT);
            while ((unsigned)(v >> 32) != exp)
                v = __hip_atomic_load(src, __ATOMIC_RELAXED, __HIP_MEMORY_SCOPE_AGENT);
            *reinterpret_cast<unsigned*>(&hl[par * 256 + pdst]) = (unsigned)v;
        }
        __syncthreads();   // barrier(st): hl[par] complete

        if (tid < 256) {
            __builtin_amdgcn_s_setprio(1);
            float xv = __half2float(xgp[(size_t)t * G4]);
            // full 256-k dot; 4 k-quarter accumulators break the dep chain
            float a0 = 0.f, a1 = 0.f, a2 = 0.f, a3 = 0.f;
            const float4* hp = reinterpret_cast<const float4*>(hl + par * 256);
            #pragma unroll
            for (int i = 0; i < 8; ++i) {
                float4 h0 = hp[i];
                float4 h1 = hp[8 + i];
                float4 h2 = hp[16 + i];
                float4 h3 = hp[24 + i];
                a0 = dot2acc(__builtin_bit_cast(f16x2, h0.x), WH(4*i+0),   a0);
                a0 = dot2acc(__builtin_bit_cast(f16x2, h0.y), WH(4*i+1),   a0);
                a0 = dot2acc(__builtin_bit_cast(f16x2, h0.z), WH(4*i+2),   a0);
                a0 = dot2acc(__builtin_bit_cast(f16x2, h0.w), WH(4*i+3),   a0);
                a1 = dot2acc(__builtin_bit_cast(f16x2, h1.x), WH(32+4*i+0), a1);
                a1 = dot2acc(__builtin_bit_cast(f16x2, h1.y), WH(32+4*i+1), a1);
                a1 = dot2acc(__builtin_bit_cast(f16x2, h1.z), WH(32+4*i+2), a1);
                a1 = dot2acc(__builtin_bit_cast(f16x2, h1.w), WH(32+4*i+3), a1);
                a2 = dot2acc(__builtin_bit_cast(f16x2, h2.x), WH(64+4*i+0), a2);
                a2 = dot2acc(__builtin_bit_cast(f16x2, h2.y), WH(64+4*i+1), a2);
                a2 = dot2acc(__builtin_bit_cast(f16x2, h2.z), WH(64+4*i+2), a2);
                a2 = dot2acc(__builtin_bit_cast(f16x2, h2.w), WH(64+4*i+3), a2);
                a3 = dot2acc(__builtin_bit_cast(f16x2, h3.x), WH(96+4*i+0), a3);
                a3 = dot2acc(__builtin_bit_cast(f16x2, h3.y), WH(96+4*i+1), a3);
                a3 = dot2acc(__builtin_bit_cast(f16x2, h3.z), WH(96+4*i+2), a3);
                a3 = dot2acc(__builtin_bit_cast(f16x2, h3.w), WH(96+4*i+3), a3);
            }
            float v = ((a0 + a1) + (a2 + a3)) + xv;   // this lane's gate value

            // gather gates within the quad: as-if-q0 mapping (correct at q==0)
            float x1 = qpermf<0xB1>(v);               // xor1
            float x2 = qpermf<0x4E>(v);               // xor2
            float x3 = qpermf<0xB1>(x2);              // xor3

            float ii = sigm(v);
            float ff = sigm(x1);
            float g2 = tanh_fast(x2);
            float oo = sigm(x3);
            c_state = ff * c_state + ii * g2;
            float h = oo * tanh_fast(c_state);        // correct at q==0 lanes

            // pair partner (next cell's h lives 4 lanes up, also q==0)
            float hpart = __shfl_down(h, 4);

            if (q == 0) {
                __half h16 = __float2half(h);
                hl[(par ^ 1) * 256 + cell_my] = h16;  // local fast path (st+1)
                if ((jl & 1) == 0) {                  // pair producer
                    unsigned payload =
                        (unsigned)__builtin_bit_cast(unsigned short, h16) |
                        ((unsigned)__builtin_bit_cast(unsigned short, __float2half(hpart)) << 16);
                    unsigned long long pv =
                        ((unsigned long long)(tagbase + (unsigned)st + 1u) << 32) | payload;
                    __hip_atomic_store(&hb[(size_t)par * 256 + jq * 32 + (jl >> 1)], pv,
                                       __ATOMIC_RELAXED, __HIP_MEMORY_SCOPE_AGENT);
                }
                outp[((size_t)b * T_LEN + t) * (2 * HID) + d * HID + cell_my] = h;
            }
            __builtin_amdgcn_s_setprio(0);
        }
        // single barrier/step: see safety proof in header.
    }
}

#define RECUR_LDS 98304u

extern "C" void kernel_launch(void* const* d_in, const int* in_sizes, int n_in,
                              void* d_out, int out_size, void* d_ws, size_t ws_size,
                              hipStream_t stream)
{
    const float* x       = (const float*)d_in[0];
    const float* W_ih_f0 = (const float*)d_in[1];
    const float* W_hh_f0 = (const float*)d_in[2];
    const float* b_ih_f0 = (const float*)d_in[3];
    const float* b_hh_f0 = (const float*)d_in[4];
    const float* W_ih_r0 = (const float*)d_in[5];
    const float* W_hh_r0 = (const float*)d_in[6];
    const float* b_ih_r0 = (const float*)d_in[7];
    const float* b_hh_r0 = (const float*)d_in[8];
    const float* W_ih_f1 = (const float*)d_in[9];
    const float* W_hh_f1 = (const float*)d_in[10];
    const float* b_ih_f1 = (const float*)d_in[11];
    const float* b_hh_f1 = (const float*)d_in[12];
    const float* W_ih_r1 = (const float*)d_in[13];
    const float* W_hh_r1 = (const float*)d_in[14];
    const float* b_ih_r1 = (const float*)d_in[15];
    const float* b_hh_r1 = (const float*)d_in[16];

    float* outp = (float*)d_out;

    __half* xg = (__half*)d_ws;
    const size_t xg_bytes = (size_t)2 * BATCH * T_LEN * G4 * sizeof(__half); // 134,217,728
    unsigned long long* hbt = (unsigned long long*)((char*)d_ws + xg_bytes); // 262,144 B

    hipFuncSetAttribute(reinterpret_cast<const void*>(recur15_kernel),
                        hipFuncAttributeMaxDynamicSharedMemorySize, RECUR_LDS);

    // clean tag space every launch (no stale-tag pre-match, fully replay-safe)
    hipMemsetAsync(hbt, 0, 262144, stream);

    // ---- layer 0 ----
    proj_mfma<<<dim3(8, 256, 2), 256, 0, stream>>>(x, 256, W_ih_f0, W_ih_r0,
        b_ih_f0, b_hh_f0, b_ih_r0, b_hh_r0, xg);
    {
        const __half* xg_c = xg;
        unsigned int base0 = 1u;
        void* args[] = {(void*)&xg_c, (void*)&W_hh_f0, (void*)&W_hh_r0,
                        (void*)&outp, (void*)&hbt, (void*)&base0};
        hipLaunchCooperativeKernel(reinterpret_cast<const void*>(recur15_kernel),
                                   dim3(256), dim3(384), args, RECUR_LDS, stream);
    }

    // ---- layer 1 ----
    proj_mfma<<<dim3(8, 256, 2), 256, 0, stream>>>(outp, 512, W_ih_f1, W_ih_r1,
        b_ih_f1, b_hh_f1, b_ih_r1, b_hh_r1, xg);
    {
        const __half* xg_c = xg;
        unsigned int base1 = 4096u;
        void* args[] = {(void*)&xg_c, (void*)&W_hh_f1, (void*)&W_hh_r1,
                        (void*)&outp, (void*)&hbt, (void*)&base1};
        hipLaunchCooperativeKernel(reinterpret_cast<const void*>(recur15_kernel),
                                   dim3(256), dim3(384), args, RECUR_LDS, stream);
    }
}

// Round 18
// 2907.797 us; speedup vs baseline: 1.2480x; 1.2480x over previous
//
#include <hip/hip_runtime.h>
#include <hip/hip_fp16.h>

// Bidirectional 2-layer LSTM: B=32, T=1024, IN=256, H=256.
// ws layout: xg  f16 [2][32][1024][1024]        = 134,217,728 B
//            hbt u64 [2][32][2 parity][256]     =     262,144 B (pair-tagged h)
// total = 134,479,872 B
//
// FINAL STRUCTURE (= r14, the empirical optimum of this family):
//   proj_mfma: fp16 MFMA 16x16x32, 128x128 tile, BK=64, f32 accumulate,
//     bias epilogue, coalesced f16 out (~130us per layer).
//   recur12: cooperative 256 wgs x 512 thr; wg = (d, b, h-quarter jq);
//     group-of-4 same-XCD (bid%8); W_hh in 64 half2 VGPRs (resident class);
//     fdot2 dots, kh-split + scr reduce, wave-0 epilogue; fence-free
//     pair-tagged u64 exchange (tag32 | 2x fp16), 96 one-slot pollers;
//     2 barriers/step. 54KB LDS pad caps occupancy -> no spill.
//   This round adds only s_sleep(1) poll backoff (reduces L3 probe contention
//   with producers' stores at the coherence point; detection granularity
//   ~64cy << RT ~1400cy).
// Step floor ~1.26us = compute 0.3 + L3-coherence RT 0.6 + barriers/epilogue.
// Deviations tried and rejected: 2-batch interleave (r15 +28%), 1-barrier
// concurrent pollers (r16 +9%), full-k layout (r17 +32%, VGPR spill).
//
// Tag protocol per (d,b) (layer base B): producer at step st stores
// (B+st+1, pair) into parity st&1; consumer at step st polls parity (st+1)&1
// for tag B+st. L0 base=1, L1 base=4096; hbt memset 0 each launch.

#define T_LEN 1024
#define BATCH 32
#define HID   256
#define G4    1024

struct __align__(16) Half8 { __half h[8]; };

typedef _Float16 f16x2 __attribute__((ext_vector_type(2)));
typedef _Float16 half8_t __attribute__((ext_vector_type(8)));
typedef float f32x4 __attribute__((ext_vector_type(4)));

__device__ __forceinline__ f16x2 pack_f16x2(float lo, float hi) {
    f16x2 r; r.x = (_Float16)lo; r.y = (_Float16)hi; return r;
}
__device__ __forceinline__ float dot2acc(f16x2 a, f16x2 b, float c) {
#if __has_builtin(__builtin_amdgcn_fdot2)
    return __builtin_amdgcn_fdot2(a, b, c, false);
#else
    return c + (float)a.x * (float)b.x + (float)a.y * (float)b.y;
#endif
}

template <int CTRL>
__device__ __forceinline__ unsigned qperm_u32(unsigned v) {
    int r = __builtin_amdgcn_update_dpp((int)v, (int)v, CTRL, 0xF, 0xF, true);
    return (unsigned)r;
}

__device__ __forceinline__ float sigm(float x) { return 1.0f / (1.0f + __expf(-x)); }
__device__ __forceinline__ float tanh_fast(float x) {
    float e = __expf(2.f * x);            // inf-safe
    return 1.f - 2.f / (e + 1.f);
}

// ---- MFMA projection: xg = A*W^T + bias, fp16 out ----
__global__ __launch_bounds__(256, 2) void proj_mfma(
    const float* __restrict__ A, int K,
    const float* __restrict__ Wf, const float* __restrict__ Wr,
    const float* __restrict__ bih_f, const float* __restrict__ bhh_f,
    const float* __restrict__ bih_r, const float* __restrict__ bhh_r,
    __half* __restrict__ xg)
{
    const int dir = blockIdx.z;
    const float* __restrict__ W   = dir ? Wr    : Wf;
    const float* __restrict__ bih = dir ? bih_r : bih_f;
    const float* __restrict__ bhh = dir ? bhh_r : bhh_f;
    __half* __restrict__ outp = xg + (size_t)dir * ((size_t)BATCH * T_LEN * G4);

    __shared__ char psm[36864];
    __half* As = (__half*)psm;                // [128][72]
    __half* Bs = (__half*)(psm + 18432);      // [128][72]

    const int tid  = threadIdx.x;
    const int lane = tid & 63;
    const int wave = tid >> 6;
    const int wm   = wave >> 1;
    const int wn   = wave & 1;
    const int fr   = lane & 15;
    const int fk   = lane >> 4;
    const int m0   = blockIdx.y * 128;
    const int n0   = blockIdx.x * 128;

    float biasv[4];
    #pragma unroll
    for (int ni = 0; ni < 4; ++ni) {
        int n = n0 + wn * 64 + ni * 16 + fr;
        biasv[ni] = bih[n] + bhh[n];
    }

    f32x4 acc[4][4];
    #pragma unroll
    for (int mi = 0; mi < 4; ++mi)
        #pragma unroll
        for (int ni = 0; ni < 4; ++ni)
            acc[mi][ni] = (f32x4){0.f, 0.f, 0.f, 0.f};

    for (int k0 = 0; k0 < K; k0 += 64) {
        #pragma unroll
        for (int it = 0; it < 4; ++it) {
            int t2  = tid + it * 256;
            int row = t2 >> 3;
            int ks  = (t2 & 7) * 8;
            const float* pa = &A[(size_t)(m0 + row) * K + k0 + ks];
            const float* pb = &W[(size_t)(n0 + row) * K + k0 + ks];
            float4 a0 = *reinterpret_cast<const float4*>(pa);
            float4 a1 = *reinterpret_cast<const float4*>(pa + 4);
            float4 b0 = *reinterpret_cast<const float4*>(pb);
            float4 b1 = *reinterpret_cast<const float4*>(pb + 4);
            Half8 ha, hb;
            ha.h[0] = __float2half(a0.x); ha.h[1] = __float2half(a0.y);
            ha.h[2] = __float2half(a0.z); ha.h[3] = __float2half(a0.w);
            ha.h[4] = __float2half(a1.x); ha.h[5] = __float2half(a1.y);
            ha.h[6] = __float2half(a1.z); ha.h[7] = __float2half(a1.w);
            hb.h[0] = __float2half(b0.x); hb.h[1] = __float2half(b0.y);
            hb.h[2] = __float2half(b0.z); hb.h[3] = __float2half(b0.w);
            hb.h[4] = __float2half(b1.x); hb.h[5] = __float2half(b1.y);
            hb.h[6] = __float2half(b1.z); hb.h[7] = __float2half(b1.w);
            *reinterpret_cast<Half8*>(&As[row * 72 + ks]) = ha;
            *reinterpret_cast<Half8*>(&Bs[row * 72 + ks]) = hb;
        }
        __syncthreads();

        #pragma unroll
        for (int kk = 0; kk < 2; ++kk) {
            half8_t af[4], bf[4];
            #pragma unroll
            for (int mi = 0; mi < 4; ++mi)
                af[mi] = *reinterpret_cast<const half8_t*>(
                    &As[(wm * 64 + mi * 16 + fr) * 72 + kk * 32 + fk * 8]);
            #pragma unroll
            for (int ni = 0; ni < 4; ++ni)
                bf[ni] = *reinterpret_cast<const half8_t*>(
                    &Bs[(wn * 64 + ni * 16 + fr) * 72 + kk * 32 + fk * 8]);
            #pragma unroll
            for (int mi = 0; mi < 4; ++mi)
                #pragma unroll
                for (int ni = 0; ni < 4; ++ni)
                    acc[mi][ni] = __builtin_amdgcn_mfma_f32_16x16x32_f16(
                        af[mi], bf[ni], acc[mi][ni], 0, 0, 0);
        }
        __syncthreads();
    }

    __half* Cs = (__half*)psm;
    #pragma unroll
    for (int mi = 0; mi < 4; ++mi)
        #pragma unroll
        for (int ni = 0; ni < 4; ++ni) {
            #pragma unroll
            for (int i = 0; i < 4; ++i) {
                int row = wm * 64 + mi * 16 + fk * 4 + i;
                int col = wn * 64 + ni * 16 + fr;
                Cs[row * 136 + col] = __float2half(acc[mi][ni][i] + biasv[ni]);
            }
        }
    __syncthreads();
    #pragma unroll
    for (int it = 0; it < 8; ++it) {
        int slot = it * 256 + tid;
        int row  = slot >> 4;
        int c8   = (slot & 15) * 8;
        Half8 v = *reinterpret_cast<const Half8*>(&Cs[row * 136 + c8]);
        *reinterpret_cast<Half8*>(&outp[(size_t)(m0 + row) * G4 + n0 + c8]) = v;
    }
}

// ---- cooperative recurrence (r14 optimum): pair-packed tagged exchange ----
// bid = jq*64 + (d*32 + b): jq = bid>>6, d = (bid>>5)&1, b = bid&31.
// thread: kh = tid>>8, r = tid&255. Gate row n = (r>>6)*256 + jq*64 + (r&63).
// W = n's k-half = 128 fp16 = 64 VGPRs. Epilogue: tid<64 (wave 0).
// Pollers: tid in [256,352) -> 96, one u64 pair-slot each.
extern "C" __global__ __launch_bounds__(512, 2) void recur12_kernel(
    const __half* __restrict__ xg,
    const float* __restrict__ Whh_f,           // [1024][256]
    const float* __restrict__ Whh_r,
    float* __restrict__ outp,                  // [32][1024][512]
    unsigned long long* __restrict__ hbt,      // [2][32][2][256] (128 used/parity)
    unsigned int tagbase)
{
    // 54 KB static LDS pad: caps occupancy at 2 blocks/CU -> VGPR budget 128.
    __shared__ char smem[55296];
    __half* hl  = (__half*)smem;            // [2 parity][256 j]
    float*  scr = (float*)(smem + 1024);    // [2 kh][256 r]

    const int tid = threadIdx.x;
    const int bid = blockIdx.x;
    const int jq  = bid >> 6;
    const int d   = (bid >> 5) & 1;
    const int b   = bid & 31;
    const float* __restrict__ Whh = d ? Whh_r : Whh_f;

    const int kh = tid >> 8;
    const int r  = tid & 255;
    const int q  = r >> 6;
    const int jl = r & 63;
    const int n_my = (q << 8) + jq * 64 + jl;

    // --- one-time: 128 fp16 weights (row n_my, k-half kh) = 64 half2 VGPRs ---
    unsigned wh[64];
    {
        const float* wrow = Whh + (size_t)n_my * HID + kh * 128;
        #pragma unroll
        for (int i = 0; i < 32; ++i) {
            float4 w4 = *reinterpret_cast<const float4*>(&wrow[i * 4]);
            wh[2 * i]     = __builtin_bit_cast(unsigned, pack_f16x2(w4.x, w4.y));
            wh[2 * i + 1] = __builtin_bit_cast(unsigned, pack_f16x2(w4.z, w4.w));
        }
    }
    #pragma unroll
    for (int i = 0; i < 64; ++i) asm volatile("" : "+v"(wh[i]));   // no remat

    unsigned long long* hb = hbt + (size_t)(d * 32 + b) * 512;   // [parity][256]

    // init: h[-1]=0 -> parity-1 pair tags (32 slots) + local stage parity-0
    if (tid < 32) {
        __hip_atomic_store(&hb[256 + jq * 32 + tid],
                           (unsigned long long)tagbase << 32,
                           __ATOMIC_RELAXED, __HIP_MEMORY_SCOPE_AGENT);
    }
    if (tid < 64) hl[0 * 256 + jq * 64 + tid] = __float2half(0.f);

    // poller role: tids [256,352) each own ONE foreign pair-slot
    const bool isPoll = (tid >= 256) && (tid < 352);
    int pslot = 0, pdst = 0;
    if (isPoll) {
        int u  = tid - 256;            // 0..95
        int fq = u >> 5;               // 0..2
        int qq = fq + (fq >= jq);      // skip own quarter
        int pi = u & 31;
        pslot  = qq * 32 + pi;
        pdst   = qq * 64 + pi * 2;     // __half index (even)
    }

    // xg: kh==0 threads add xg(b, n_my)
    const __half* __restrict__ xgp =
        xg + ((size_t)(d * BATCH + b)) * T_LEN * G4 + n_my;

    float c_state = 0.f;               // tid<64: cell j = jq*64 + tid

    for (int st = 0; st < T_LEN; ++st) {
        const int t = d ? (T_LEN - 1 - st) : st;

        // prefetch xg (independent of h) before polling
        float xv = (kh == 0) ? __half2float(xgp[(size_t)t * G4]) : 0.f;

        __half* hlcur = hl + (st & 1) * 256;

        // stage foreign quarters (parity (st+1)&1, tag tagbase+st)
        if (isPoll) {
            const unsigned int exp = tagbase + (unsigned)st;
            unsigned long long* src = hb + (size_t)((st + 1) & 1) * 256 + pslot;
            unsigned long long v =
                __hip_atomic_load(src, __ATOMIC_RELAXED, __HIP_MEMORY_SCOPE_AGENT);
            while ((unsigned int)(v >> 32) != exp) {
                __builtin_amdgcn_s_sleep(1);   // backoff: cut L3 probe contention
                v = __hip_atomic_load(src, __ATOMIC_RELAXED, __HIP_MEMORY_SCOPE_AGENT);
            }
            *reinterpret_cast<unsigned*>(&hlcur[pdst]) = (unsigned)v;   // 2 fp16
        }
        __syncthreads();   // hl[st&1] complete

        // 128-k dot: W in 64 half2 VGPRs, h via broadcast ds_read_b128
        float a0 = xv, a1 = 0.f;
        {
            const float4* hp = reinterpret_cast<const float4*>(hlcur + kh * 128);
            #pragma unroll
            for (int i = 0; i < 16; ++i) {
                float4 hv = hp[i];
                a0 = dot2acc(__builtin_bit_cast(f16x2, hv.x), __builtin_bit_cast(f16x2, wh[4 * i + 0]), a0);
                a1 = dot2acc(__builtin_bit_cast(f16x2, hv.y), __builtin_bit_cast(f16x2, wh[4 * i + 1]), a1);
                a0 = dot2acc(__builtin_bit_cast(f16x2, hv.z), __builtin_bit_cast(f16x2, wh[4 * i + 2]), a0);
                a1 = dot2acc(__builtin_bit_cast(f16x2, hv.w), __builtin_bit_cast(f16x2, wh[4 * i + 3]), a1);
            }
        }
        scr[kh * 256 + r] = a0 + a1;
        __syncthreads();

        if (tid < 64) {   // epilogue = wave 0 exactly
            float gi = scr[      tid] + scr[256 +       tid];
            float gf = scr[ 64 + tid] + scr[256 +  64 + tid];
            float gg = scr[128 + tid] + scr[256 + 128 + tid];
            float go = scr[192 + tid] + scr[256 + 192 + tid];
            float ii = sigm(gi);
            float ff = sigm(gf);
            float g2 = tanh_fast(gg);
            float oo = sigm(go);
            c_state = ff * c_state + ii * g2;
            float h = oo * tanh_fast(c_state);
            const int j = jq * 64 + tid;

            // local fast path (read at st+1 from hl[(st+1)&1])
            __half h16 = __float2half(h);
            hl[((st + 1) & 1) * 256 + j] = h16;

            // pair-pack via quad_perm (lane^1 neighbor), even lanes store
            unsigned hbits = (unsigned)__builtin_bit_cast(unsigned short, h16);
            unsigned nb = qperm_u32<0xB1>(hbits);      // lane j <- h of j^1
            if ((tid & 1) == 0) {
                unsigned payload = hbits | (nb << 16); // cells 2p (lo), 2p+1 (hi)
                unsigned long long pv =
                    ((unsigned long long)(tagbase + (unsigned)st + 1u) << 32) | payload;
                __hip_atomic_store(&hb[(size_t)(st & 1) * 256 + jq * 32 + (tid >> 1)], pv,
                                   __ATOMIC_RELAXED, __HIP_MEMORY_SCOPE_AGENT);
            }
            outp[((size_t)b * T_LEN + t) * (2 * HID) + d * HID + j] = h;
        }
        // no 3rd barrier: next step's post-stage barrier orders scr reuse; the
        // epilogue's hl[(st+1)&1] writes are to slots disjoint from pollers'.
    }
}

extern "C" void kernel_launch(void* const* d_in, const int* in_sizes, int n_in,
                              void* d_out, int out_size, void* d_ws, size_t ws_size,
                              hipStream_t stream)
{
    const float* x       = (const float*)d_in[0];
    const float* W_ih_f0 = (const float*)d_in[1];
    const float* W_hh_f0 = (const float*)d_in[2];
    const float* b_ih_f0 = (const float*)d_in[3];
    const float* b_hh_f0 = (const float*)d_in[4];
    const float* W_ih_r0 = (const float*)d_in[5];
    const float* W_hh_r0 = (const float*)d_in[6];
    const float* b_ih_r0 = (const float*)d_in[7];
    const float* b_hh_r0 = (const float*)d_in[8];
    const float* W_ih_f1 = (const float*)d_in[9];
    const float* W_hh_f1 = (const float*)d_in[10];
    const float* b_ih_f1 = (const float*)d_in[11];
    const float* b_hh_f1 = (const float*)d_in[12];
    const float* W_ih_r1 = (const float*)d_in[13];
    const float* W_hh_r1 = (const float*)d_in[14];
    const float* b_ih_r1 = (const float*)d_in[15];
    const float* b_hh_r1 = (const float*)d_in[16];

    float* outp = (float*)d_out;

    __half* xg = (__half*)d_ws;
    const size_t xg_bytes = (size_t)2 * BATCH * T_LEN * G4 * sizeof(__half); // 134,217,728
    unsigned long long* hbt = (unsigned long long*)((char*)d_ws + xg_bytes); // 262,144 B

    // clean tag space every launch (no stale-tag pre-match, fully replay-safe)
    hipMemsetAsync(hbt, 0, 262144, stream);

    // ---- layer 0 ----
    proj_mfma<<<dim3(8, 256, 2), 256, 0, stream>>>(x, 256, W_ih_f0, W_ih_r0,
        b_ih_f0, b_hh_f0, b_ih_r0, b_hh_r0, xg);
    {
        const __half* xg_c = xg;
        unsigned int base0 = 1u;
        void* args[] = {(void*)&xg_c, (void*)&W_hh_f0, (void*)&W_hh_r0,
                        (void*)&outp, (void*)&hbt, (void*)&base0};
        hipLaunchCooperativeKernel(reinterpret_cast<const void*>(recur12_kernel),
                                   dim3(256), dim3(512), args, 0, stream);
    }

    // ---- layer 1 ----
    proj_mfma<<<dim3(8, 256, 2), 256, 0, stream>>>(outp, 512, W_ih_f1, W_ih_r1,
        b_ih_f1, b_hh_f1, b_ih_r1, b_hh_r1, xg);
    {
        const __half* xg_c = xg;
        unsigned int base1 = 4096u;
        void* args[] = {(void*)&xg_c, (void*)&W_hh_f1, (void*)&W_hh_r1,
                        (void*)&outp, (void*)&hbt, (void*)&base1};
        hipLaunchCooperativeKernel(reinterpret_cast<const void*>(recur12_kernel),
                                   dim3(256), dim3(512), args, 0, stream);
    }
}